// Round 15
// baseline (87.117 us; speedup 1.0000x reference)
//
#include <hip/hip_runtime.h>
#include <hip/hip_bf16.h>

#define N_UTT 4000
#define NDIM 256
#define B_DIA 100
#define L_DIA 40
#define NLAYERS 4
#define NT 256          // 4 waves = 1 wave/SIMD -> 512-VGPR budget per wave

typedef __attribute__((ext_vector_type(8))) short short8;   // 8 bf16 (4 VGPRs)
typedef __attribute__((ext_vector_type(4))) float f32x4;    // MFMA acc

union bfpk4 { __hip_bfloat16 h[4]; uint2 u; };

static __device__ __forceinline__ float bf2f(__hip_bfloat16 h) {
  union { float f; unsigned u; } x;
  x.u = ((unsigned)*(unsigned short*)&h) << 16;
  return x.f;
}

// ---------------------------------------------------------------------------
// K_wt: weight transpose+bf16 via LDS tile: Wt[g][n][k] = W_g[k][n]
__global__ void k_wt(const float* __restrict__ W0, const float* __restrict__ Wc,
                     __hip_bfloat16* __restrict__ Wt) {
  int k0 = blockIdx.x * 64, n0 = blockIdx.y * 64, g = blockIdx.z;
  int t = threadIdx.x;
  const float* src = (g == 0) ? W0 : (Wc + (g - 1) * NDIM * NDIM);
  __shared__ float tile[64][65];
  #pragma unroll
  for (int it = 0; it < 16; it++) {
    int e = t + 256 * it;
    int row = e >> 6, col = e & 63;
    tile[row][col] = src[(k0 + row) * NDIM + n0 + col];
  }
  __syncthreads();
  #pragma unroll
  for (int it = 0; it < 16; it++) {
    int e = t + 256 * it;
    int row = e >> 6, col = e & 63;
    Wt[(g * NDIM + n0 + row) * NDIM + k0 + col] = __float2bfloat16(tile[col][row]);
  }
}

// ---------------------------------------------------------------------------
// K_main: one block per dialogue; whole network LDS-resident.
// 4 waves (1/SIMD, 512-VGPR budget): wave w owns cols [64w, 64w+64) (c=4).
// Per k-step: af[9] + bfw[4] = 13 LDS b128 for 36 MFMA (vs 11:18 at 8 waves).
__global__ __launch_bounds__(NT, 1) void k_main(
    const float* __restrict__ a, const float* __restrict__ v,
    const float* __restrict__ lf, const float* __restrict__ qmask,
    const float* __restrict__ spk, const float* __restrict__ b0,
    const __hip_bfloat16* __restrict__ Wt, float* __restrict__ out) {
  __shared__ __hip_bfloat16 xls[3][L_DIA][264];    // x, then sup   (63,360 B)
  __shared__ __hip_bfloat16 hls[3][NDIM][L_DIA];   // h transposed  (61,440 B)
  __shared__ __hip_bfloat16 sext[3][L_DIA][136];   // A_ext K=128   (32,640 B)
  __shared__ float invn[120];
  __shared__ float dinv[120];
  __shared__ float psum[120][4];

  int b = blockIdx.x;
  int t = threadIdx.x;
  int w = t >> 6, ln = t & 63;
  int l15 = ln & 15, lk = (ln >> 4) * 8;
  int hi4 = (ln >> 4) * 4;
  const float inv_pi = 0.31830988618379067f;

  int arows[3], cols[4];
  #pragma unroll
  for (int rt = 0; rt < 3; rt++) {
    int rr_ = rt * 16 + l15;
    arows[rt] = (rr_ < L_DIA) ? rr_ : (L_DIA - 1);
  }
  #pragma unroll
  for (int c = 0; c < 4; c++) cols[c] = w * 64 + c * 16 + l15;

  // ---- phase A: zero sext; build x; write out-x; x -> xls bf16 ----
  {
    unsigned int* sz = (unsigned int*)&sext[0][0][0];
    for (int e = t; e < 3 * L_DIA * 136 / 2; e += NT) sz[e] = 0u;
  }
  for (int e = t; e < 120 * 64; e += NT) {
    int r = e >> 6, c4 = e & 63;
    int m = r / L_DIA, p = r - m * L_DIA;
    int i = b * L_DIA + p;
    float4 val;
    if (m == 0)      val = ((const float4*)a)[i * 64 + c4];
    else if (m == 1) val = ((const float4*)v)[i * 64 + c4];
    else {
      val = ((const float4*)lf)[i * 64 + c4];
      float q0 = qmask[(p * B_DIA + b) * 2 + 0];
      float q1 = qmask[(p * B_DIA + b) * 2 + 1];
      int s = (q1 > q0) ? 1 : 0;
      float4 sv = ((const float4*)spk)[s * 64 + c4];
      val.x += sv.x; val.y += sv.y; val.z += sv.z; val.w += sv.w;
    }
    ((float4*)out)[i * 384 + m * 128 + c4] = val;
    bfpk4 pk;
    pk.h[0] = __float2bfloat16(val.x); pk.h[1] = __float2bfloat16(val.y);
    pk.h[2] = __float2bfloat16(val.z); pk.h[3] = __float2bfloat16(val.w);
    *(uint2*)&xls[m][p][c4 * 4] = pk.u;
  }
  __syncthreads();

  // ---- row inverse norms (vectorized) ----
  for (int it = t; it < 480; it += NT) {
    int r = it >> 2, q4 = it & 3;
    int m = r / L_DIA, p = r - m * L_DIA;
    float s = 0.f;
    #pragma unroll
    for (int jj = 0; jj < 8; jj++) {
      short8 vv = *(const short8*)&xls[m][p][q4 * 64 + jj * 8];
      #pragma unroll
      for (int e = 0; e < 8; e++) {
        union { float f; unsigned u; } x;
        x.u = ((unsigned)(unsigned short)vv[e]) << 16;
        s += x.f * x.f;
      }
    }
    psum[r][q4] = s;
  }
  __syncthreads();
  if (t < 120) invn[t] = rsqrtf(psum[t][0] + psum[t][1] + psum[t][2] + psum[t][3]);
  __syncthreads();

  // ---- phase B: waves 0-2 self-sim 3x3; wave 3 loops the 3 pair diagonals ----
  if (w < 3) {
    int mA = w;
    f32x4 sacc[3][3];
    #pragma unroll
    for (int rt = 0; rt < 3; rt++)
      #pragma unroll
      for (int ct = 0; ct < 3; ct++) sacc[rt][ct] = (f32x4){0.f,0.f,0.f,0.f};
    #pragma unroll
    for (int k0 = 0; k0 < NDIM; k0 += 32) {
      short8 fr[3];
      #pragma unroll
      for (int rt = 0; rt < 3; rt++)
        fr[rt] = *(const short8*)&xls[mA][arows[rt]][k0 + lk];
      #pragma unroll
      for (int rt = 0; rt < 3; rt++)
        #pragma unroll
        for (int ct = 0; ct < 3; ct++)
          sacc[rt][ct] = __builtin_amdgcn_mfma_f32_16x16x32_bf16(fr[rt], fr[ct], sacc[rt][ct], 0, 0, 0);
    }
    #pragma unroll
    for (int rt = 0; rt < 3; rt++)
      #pragma unroll
      for (int ct = 0; ct < 3; ct++)
        #pragma unroll
        for (int rr = 0; rr < 4; rr++) {
          int row = rt * 16 + hi4 + rr;
          int col = ct * 16 + l15;
          if (row < L_DIA && col < L_DIA) {
            float cs = sacc[rt][ct][rr] * invn[mA * 40 + row] * invn[mA * 40 + col] * 0.99999f;
            cs = fminf(fmaxf(cs, -1.f), 1.f);
            sext[mA][row][col] = __float2bfloat16(1.f - acosf(cs) * inv_pi);
          }
        }
  } else {
    #pragma unroll
    for (int pi = 0; pi < 3; pi++) {
      int mA = (pi == 2) ? 1 : 0, mB = (pi == 0) ? 1 : 2;
      int slotA = (pi == 0) ? 40 : 80, slotB = (pi == 2) ? 80 : 40;
      f32x4 dacc[3];
      #pragma unroll
      for (int rt = 0; rt < 3; rt++) dacc[rt] = (f32x4){0.f,0.f,0.f,0.f};
      #pragma unroll
      for (int k0 = 0; k0 < NDIM; k0 += 32) {
        short8 frA[3], frB[3];
        #pragma unroll
        for (int rt = 0; rt < 3; rt++) {
          frA[rt] = *(const short8*)&xls[mA][arows[rt]][k0 + lk];
          frB[rt] = *(const short8*)&xls[mB][arows[rt]][k0 + lk];
        }
        #pragma unroll
        for (int rt = 0; rt < 3; rt++)
          dacc[rt] = __builtin_amdgcn_mfma_f32_16x16x32_bf16(frA[rt], frB[rt], dacc[rt], 0, 0, 0);
      }
      #pragma unroll
      for (int rt = 0; rt < 3; rt++)
        #pragma unroll
        for (int rr = 0; rr < 4; rr++) {
          int row = rt * 16 + hi4 + rr;
          if (l15 == (hi4 + rr) && row < L_DIA) {
            float cs = dacc[rt][rr] * invn[mA * 40 + row] * invn[mB * 40 + row] * 0.99999f;
            cs = fminf(fmaxf(cs, -1.f), 1.f);
            __hip_bfloat16 vv = __float2bfloat16(1.f - acosf(cs) * inv_pi);
            sext[mA][row][slotA + row] = vv;
            sext[mB][row][slotB + row] = vv;
          }
        }
    }
  }
  __syncthreads();

  // ---- degrees -> dinv ----
  if (t < 120) {
    int m = t / 40, p = t - m * 40;
    float d = 0.f;
    #pragma unroll 10
    for (int q = 0; q < 40; q++) d += bf2f(sext[m][p][q]);
    d += bf2f(sext[m][p][40 + p]) + bf2f(sext[m][p][80 + p]);
    dinv[t] = rsqrtf(d);
  }
  __syncthreads();
  // ---- normalize sext in place (fold 0.9) ----
  for (int e = t; e < 5040; e += NT) {
    if (e < 4800) {
      int m = e / 1600, rem = e - m * 1600;
      int p = rem / 40, q = rem - p * 40;
      sext[m][p][q] = __float2bfloat16(
          bf2f(sext[m][p][q]) * 0.9f * dinv[m * 40 + p] * dinv[m * 40 + q]);
    } else {
      int idx = e - 4800;
      int m = idx / 80, j = idx - m * 80;
      int which = j / 40, p = j - which * 40;
      int pmx = which ? ((m == 2) ? 1 : 2) : ((m == 0) ? 1 : 0);
      int k = 40 * (1 + which) + p;
      sext[m][p][k] = __float2bfloat16(
          bf2f(sext[m][p][k]) * 0.9f * dinv[m * 40 + p] * dinv[pmx * 40 + p]);
    }
  }
  __syncthreads();

  // ---- phase C: h0 = relu(x @ W0 + b0), k-outer blocked, c=4 ----
  uint2 h0r[9][4];
  {
    f32x4 acc[9][4];
    #pragma unroll
    for (int s = 0; s < 9; s++)
      #pragma unroll
      for (int c = 0; c < 4; c++) acc[s][c] = (f32x4){0.f,0.f,0.f,0.f};
    #pragma unroll
    for (int k0 = 0; k0 < NDIM; k0 += 32) {
      short8 bfw[4];
      #pragma unroll
      for (int c = 0; c < 4; c++)
        bfw[c] = *(const short8*)&Wt[cols[c] * NDIM + k0 + lk];
      short8 af[9];
      #pragma unroll
      for (int s = 0; s < 9; s++)
        af[s] = *(const short8*)&xls[s / 3][arows[s % 3]][k0 + lk];
      #pragma unroll
      for (int s = 0; s < 9; s++)
        #pragma unroll
        for (int c = 0; c < 4; c++)
          acc[s][c] = __builtin_amdgcn_mfma_f32_16x16x32_bf16(af[s], bfw[c], acc[s][c], 0, 0, 0);
    }
    #pragma unroll
    for (int s = 0; s < 9; s++) {
      int p0 = (s % 3) * 16 + hi4;
      #pragma unroll
      for (int c = 0; c < 4; c++) {
        float bias = b0[cols[c]];
        bfpk4 pk;
        #pragma unroll
        for (int rr = 0; rr < 4; rr++)
          pk.h[rr] = __float2bfloat16(fmaxf(acc[s][c][rr] + bias, 0.f));
        h0r[s][c] = pk.u;
        if (p0 < L_DIA) *(uint2*)&hls[s / 3][cols[c]][p0] = pk.u;
      }
    }
  }
  __syncthreads();

  // ---- 4 GCN layers ----
  const float thetas[NLAYERS] = {0.40546510810816438f, 0.22314355131420976f,
                                 0.15415067982725836f, 0.11778303565638346f};
  #pragma unroll
  for (int li = 0; li < NLAYERS; li++) {
    float th = thetas[li], onemt = 1.f - th;
    const __hip_bfloat16* Wl = Wt + (li + 1) * NDIM * NDIM;

    // stage 1: sup = S_ext @ [h;h_pm0;h_pm1] + 0.1*h0 -> xls (bf16)
    {
      f32x4 acc[9][4];
      #pragma unroll
      for (int s = 0; s < 9; s++)
        #pragma unroll
        for (int c = 0; c < 4; c++) acc[s][c] = (f32x4){0.f,0.f,0.f,0.f};
      #pragma unroll
      for (int j = 0; j < 4; j++) {
        int kk = j * 32 + lk;
        short8 bfv[3][4];
        #pragma unroll
        for (int mm = 0; mm < 3; mm++) {
          int pm0 = (mm == 0) ? 1 : 0, pm1 = (mm == 2) ? 1 : 2;
          int srcm, brow;
          if (kk < 40)       { srcm = mm;  brow = kk; }
          else if (kk < 80)  { srcm = pm0; brow = kk - 40; }
          else if (kk < 120) { srcm = pm1; brow = kk - 80; }
          else               { srcm = pm1; brow = 32; }   // af zero there
          #pragma unroll
          for (int c = 0; c < 4; c++)
            bfv[mm][c] = *(const short8*)&hls[srcm][cols[c]][brow];
        }
        short8 af[9];
        #pragma unroll
        for (int s = 0; s < 9; s++)
          af[s] = *(const short8*)&sext[s / 3][arows[s % 3]][j * 32 + lk];
        #pragma unroll
        for (int s = 0; s < 9; s++)
          #pragma unroll
          for (int c = 0; c < 4; c++)
            acc[s][c] = __builtin_amdgcn_mfma_f32_16x16x32_bf16(af[s], bfv[s / 3][c], acc[s][c], 0, 0, 0);
      }
      #pragma unroll
      for (int s = 0; s < 9; s++) {
        int m = s / 3;
        int p0 = (s % 3) * 16 + hi4;
        #pragma unroll
        for (int c = 0; c < 4; c++) {
          bfpk4 h0p; h0p.u = h0r[s][c];
          if (p0 < L_DIA) {
            #pragma unroll
            for (int rr = 0; rr < 4; rr++)
              xls[m][p0 + rr][cols[c]] =
                  __float2bfloat16(acc[s][c][rr] + 0.1f * bf2f(h0p.h[rr]));
          }
        }
      }
    }
    __syncthreads();

    // stage 2: h_new = relu(theta*(sup@W) + (1-theta)*sup)
    {
      f32x4 o[9][4];
      #pragma unroll
      for (int s = 0; s < 9; s++)
        #pragma unroll
        for (int c = 0; c < 4; c++) o[s][c] = (f32x4){0.f,0.f,0.f,0.f};
      #pragma unroll
      for (int k0 = 0; k0 < NDIM; k0 += 32) {
        short8 bfw[4];
        #pragma unroll
        for (int c = 0; c < 4; c++)
          bfw[c] = *(const short8*)&Wl[cols[c] * NDIM + k0 + lk];
        short8 af[9];
        #pragma unroll
        for (int s = 0; s < 9; s++)
          af[s] = *(const short8*)&xls[s / 3][arows[s % 3]][k0 + lk];
        #pragma unroll
        for (int s = 0; s < 9; s++)
          #pragma unroll
          for (int c = 0; c < 4; c++)
            o[s][c] = __builtin_amdgcn_mfma_f32_16x16x32_bf16(af[s], bfw[c], o[s][c], 0, 0, 0);
      }
      #pragma unroll
      for (int s = 0; s < 9; s++) {
        int m = s / 3;
        int p0 = (s % 3) * 16 + hi4;
        if (p0 >= L_DIA) continue;
        #pragma unroll
        for (int c = 0; c < 4; c++) {
          int col = cols[c];
          if (li < NLAYERS - 1) {
            bfpk4 pk;
            #pragma unroll
            for (int rr = 0; rr < 4; rr++) {
              float supv = bf2f(xls[m][p0 + rr][col]);
              pk.h[rr] = __float2bfloat16(fmaxf(th * o[s][c][rr] + onemt * supv, 0.f));
            }
            *(uint2*)&hls[m][col][p0] = pk.u;
          } else {
            #pragma unroll
            for (int rr = 0; rr < 4; rr++) {
              float supv = bf2f(xls[m][p0 + rr][col]);
              out[(b * L_DIA + p0 + rr) * 1536 + m * 512 + 256 + col] =
                  fmaxf(th * o[s][c][rr] + onemt * supv, 0.f);
            }
          }
        }
      }
    }
    __syncthreads();
  }
}

// ---------------------------------------------------------------------------
extern "C" void kernel_launch(void* const* d_in, const int* in_sizes, int n_in,
                              void* d_out, int out_size, void* d_ws, size_t ws_size,
                              hipStream_t stream) {
  const float* a     = (const float*)d_in[0];
  const float* v     = (const float*)d_in[1];
  const float* lf    = (const float*)d_in[2];
  const float* qmask = (const float*)d_in[3];
  const float* spk   = (const float*)d_in[4];
  const float* W0    = (const float*)d_in[5];
  const float* b0    = (const float*)d_in[6];
  const float* Wc    = (const float*)d_in[7];
  float* out = (float*)d_out;

  __hip_bfloat16* Wt = (__hip_bfloat16*)d_ws;   // 5*256*256 bf16 = 640 KB

  k_wt<<<dim3(4, 4, 5), 256, 0, stream>>>(W0, Wc, Wt);
  k_main<<<B_DIA, NT, 0, stream>>>(a, v, lf, qmask, spk, b0, Wt, out);
}

// Round 16
// 84.123 us; speedup vs baseline: 1.0356x; 1.0356x over previous
//
#include <hip/hip_runtime.h>
#include <hip/hip_bf16.h>

#define N_UTT 4000
#define NDIM 256
#define B_DIA 100
#define L_DIA 40
#define NLAYERS 4
#define XSTR 264   // xls row stride (bf16): 528B = 33*16B aligned, 2-way banks

typedef __attribute__((ext_vector_type(8))) short short8;   // 8 bf16 (4 VGPRs)
typedef __attribute__((ext_vector_type(4))) float f32x4;    // MFMA acc

union bfpk4 { __hip_bfloat16 h[4]; uint2 u; };

static __device__ __forceinline__ float bf2f(__hip_bfloat16 h) {
  union { float f; unsigned u; } x;
  x.u = ((unsigned)*(unsigned short*)&h) << 16;
  return x.f;
}

// ---------------------------------------------------------------------------
// K_wt: weight transpose+bf16 via LDS tile: Wt[g][n][k] = W_g[k][n]
__global__ void k_wt(const float* __restrict__ W0, const float* __restrict__ Wc,
                     __hip_bfloat16* __restrict__ Wt) {
  int k0 = blockIdx.x * 64, n0 = blockIdx.y * 64, g = blockIdx.z;
  int t = threadIdx.x;
  const float* src = (g == 0) ? W0 : (Wc + (g - 1) * NDIM * NDIM);
  __shared__ float tile[64][65];
  #pragma unroll
  for (int it = 0; it < 16; it++) {
    int e = t + 256 * it;
    int row = e >> 6, col = e & 63;
    tile[row][col] = src[(k0 + row) * NDIM + n0 + col];
  }
  __syncthreads();
  #pragma unroll
  for (int it = 0; it < 16; it++) {
    int e = t + 256 * it;
    int row = e >> 6, col = e & 63;
    Wt[(g * NDIM + n0 + row) * NDIM + k0 + col] = __float2bfloat16(tile[col][row]);
  }
}

// ---------------------------------------------------------------------------
// K_main: one block per dialogue; LDS-resident network.
// xls is a single stacked [120][XSTR] matrix (row = m*40+p): x, then sup.
// Phase C & stage 2 use a 2x4 wave partition (rg = w>>2 row-group of 4
// 16-row tiles over stacked M=120(pad 128); cg = w&3 col-group of 64):
// per k-step af[4] LDS + bfw[4] global for 16 MFMA (vs round-9's 9+2 for 18).
// Stage 1 keeps the per-modality round-9 form (B operand is m-dependent);
// its 0.1*h0 blend reads the gh0 global slab written by phase C.
__global__ __launch_bounds__(512, 1) void k_main(
    const float* __restrict__ a, const float* __restrict__ v,
    const float* __restrict__ lf, const float* __restrict__ qmask,
    const float* __restrict__ spk, const float* __restrict__ b0,
    const __hip_bfloat16* __restrict__ Wt, __hip_bfloat16* __restrict__ gh0,
    float* __restrict__ out) {
  __shared__ __hip_bfloat16 xls[120 * XSTR];       // 63,360 B
  __shared__ __hip_bfloat16 hls[3][NDIM][L_DIA];   // 61,440 B
  __shared__ __hip_bfloat16 sext[3][L_DIA][136];   // 32,640 B
  __shared__ float invn[120];
  __shared__ float dinv[120];
  __shared__ float psum[120][4];
  // total 160,320 B <= 163,840

  int b = blockIdx.x;
  int t = threadIdx.x;
  int w = t >> 6, ln = t & 63;
  int l15 = ln & 15, lk = (ln >> 4) * 8;
  int hi4 = (ln >> 4) * 4;
  const float inv_pi = 0.31830988618379067f;
  __hip_bfloat16* gh0d = gh0 + b * (3 * NDIM * 48);   // per-dialogue slab

  int arows[3], cols[2];
  #pragma unroll
  for (int rt = 0; rt < 3; rt++) {
    int rr_ = rt * 16 + l15;
    arows[rt] = (rr_ < L_DIA) ? rr_ : (L_DIA - 1);
  }
  #pragma unroll
  for (int c = 0; c < 2; c++) cols[c] = w * 32 + c * 16 + l15;

  // stacked-partition geometry for phase C / stage 2
  int rg = w >> 2, cg = w & 3;
  int srows[4], cols4[4];
  #pragma unroll
  for (int i = 0; i < 4; i++) {
    int rr_ = rg * 64 + i * 16 + l15;
    srows[i] = (rr_ < 120) ? rr_ : 119;
  }
  #pragma unroll
  for (int cc = 0; cc < 4; cc++) cols4[cc] = cg * 64 + cc * 16 + l15;

  // ---- phase A: zero sext; build x; write out-x; x -> xls bf16 ----
  {
    unsigned int* sz = (unsigned int*)&sext[0][0][0];
    #pragma unroll
    for (int e = t; e < 3 * L_DIA * 136 / 2; e += 512) sz[e] = 0u;
  }
  for (int e = t; e < 120 * 64; e += 512) {
    int r = e >> 6, c4 = e & 63;
    int m = r / L_DIA, p = r - m * L_DIA;
    int i = b * L_DIA + p;
    float4 val;
    if (m == 0)      val = ((const float4*)a)[i * 64 + c4];
    else if (m == 1) val = ((const float4*)v)[i * 64 + c4];
    else {
      val = ((const float4*)lf)[i * 64 + c4];
      float q0 = qmask[(p * B_DIA + b) * 2 + 0];
      float q1 = qmask[(p * B_DIA + b) * 2 + 1];
      int s = (q1 > q0) ? 1 : 0;
      float4 sv = ((const float4*)spk)[s * 64 + c4];
      val.x += sv.x; val.y += sv.y; val.z += sv.z; val.w += sv.w;
    }
    ((float4*)out)[i * 384 + m * 128 + c4] = val;
    bfpk4 pk;
    pk.h[0] = __float2bfloat16(val.x); pk.h[1] = __float2bfloat16(val.y);
    pk.h[2] = __float2bfloat16(val.z); pk.h[3] = __float2bfloat16(val.w);
    *(uint2*)&xls[r * XSTR + c4 * 4] = pk.u;
  }
  __syncthreads();

  // ---- row inverse norms (vectorized) ----
  if (t < 480) {
    int r = t >> 2, q4 = t & 3;
    float s = 0.f;
    #pragma unroll
    for (int jj = 0; jj < 8; jj++) {
      short8 vv = *(const short8*)&xls[r * XSTR + q4 * 64 + jj * 8];
      #pragma unroll
      for (int e = 0; e < 8; e++) {
        union { float f; unsigned u; } x;
        x.u = ((unsigned)(unsigned short)vv[e]) << 16;
        s += x.f * x.f;
      }
    }
    psum[r][q4] = s;
  }
  __syncthreads();
  if (t < 120) invn[t] = rsqrtf(psum[t][0] + psum[t][1] + psum[t][2] + psum[t][3]);
  __syncthreads();

  // ---- phase B: waves 0-2 self-sim 3x3; waves 3-5 pair diagonals ----
  if (w < 3) {
    int mA = w;
    f32x4 sacc[3][3];
    #pragma unroll
    for (int rt = 0; rt < 3; rt++)
      #pragma unroll
      for (int ct = 0; ct < 3; ct++) sacc[rt][ct] = (f32x4){0.f,0.f,0.f,0.f};
    #pragma unroll
    for (int k0 = 0; k0 < NDIM; k0 += 32) {
      short8 fr[3];
      #pragma unroll
      for (int rt = 0; rt < 3; rt++)
        fr[rt] = *(const short8*)&xls[(mA * 40 + arows[rt]) * XSTR + k0 + lk];
      #pragma unroll
      for (int rt = 0; rt < 3; rt++)
        #pragma unroll
        for (int ct = 0; ct < 3; ct++)
          sacc[rt][ct] = __builtin_amdgcn_mfma_f32_16x16x32_bf16(fr[rt], fr[ct], sacc[rt][ct], 0, 0, 0);
    }
    #pragma unroll
    for (int rt = 0; rt < 3; rt++)
      #pragma unroll
      for (int ct = 0; ct < 3; ct++)
        #pragma unroll
        for (int rr = 0; rr < 4; rr++) {
          int row = rt * 16 + hi4 + rr;
          int col = ct * 16 + l15;
          if (row < L_DIA && col < L_DIA) {
            float cs = sacc[rt][ct][rr] * invn[mA * 40 + row] * invn[mA * 40 + col] * 0.99999f;
            cs = fminf(fmaxf(cs, -1.f), 1.f);
            sext[mA][row][col] = __float2bfloat16(1.f - acosf(cs) * inv_pi);
          }
        }
  } else if (w < 6) {
    int pi = w - 3;
    int mA = (pi == 2) ? 1 : 0, mB = (pi == 0) ? 1 : 2;
    int slotA = (pi == 0) ? 40 : 80, slotB = (pi == 2) ? 80 : 40;
    f32x4 dacc[3];
    #pragma unroll
    for (int rt = 0; rt < 3; rt++) dacc[rt] = (f32x4){0.f,0.f,0.f,0.f};
    #pragma unroll
    for (int k0 = 0; k0 < NDIM; k0 += 32) {
      short8 frA[3], frB[3];
      #pragma unroll
      for (int rt = 0; rt < 3; rt++) {
        frA[rt] = *(const short8*)&xls[(mA * 40 + arows[rt]) * XSTR + k0 + lk];
        frB[rt] = *(const short8*)&xls[(mB * 40 + arows[rt]) * XSTR + k0 + lk];
      }
      #pragma unroll
      for (int rt = 0; rt < 3; rt++)
        dacc[rt] = __builtin_amdgcn_mfma_f32_16x16x32_bf16(frA[rt], frB[rt], dacc[rt], 0, 0, 0);
    }
    #pragma unroll
    for (int rt = 0; rt < 3; rt++)
      #pragma unroll
      for (int rr = 0; rr < 4; rr++) {
        int row = rt * 16 + hi4 + rr;
        if (l15 == (hi4 + rr) && row < L_DIA) {
          float cs = dacc[rt][rr] * invn[mA * 40 + row] * invn[mB * 40 + row] * 0.99999f;
          cs = fminf(fmaxf(cs, -1.f), 1.f);
          __hip_bfloat16 vv = __float2bfloat16(1.f - acosf(cs) * inv_pi);
          sext[mA][row][slotA + row] = vv;
          sext[mB][row][slotB + row] = vv;
        }
      }
  }
  __syncthreads();

  // ---- degrees -> dinv ----
  if (t < 120) {
    int m = t / 40, p = t - m * 40;
    float d = 0.f;
    #pragma unroll 10
    for (int q = 0; q < 40; q++) d += bf2f(sext[m][p][q]);
    d += bf2f(sext[m][p][40 + p]) + bf2f(sext[m][p][80 + p]);
    dinv[t] = rsqrtf(d);
  }
  __syncthreads();
  // ---- normalize sext in place (fold 0.9) ----
  for (int e = t; e < 5040; e += 512) {
    if (e < 4800) {
      int m = e / 1600, rem = e - m * 1600;
      int p = rem / 40, q = rem - p * 40;
      sext[m][p][q] = __float2bfloat16(
          bf2f(sext[m][p][q]) * 0.9f * dinv[m * 40 + p] * dinv[m * 40 + q]);
    } else {
      int idx = e - 4800;
      int m = idx / 80, j = idx - m * 80;
      int which = j / 40, p = j - which * 40;
      int pmx = which ? ((m == 2) ? 1 : 2) : ((m == 0) ? 1 : 0);
      int k = 40 * (1 + which) + p;
      sext[m][p][k] = __float2bfloat16(
          bf2f(sext[m][p][k]) * 0.9f * dinv[m * 40 + p] * dinv[pmx * 40 + p]);
    }
  }
  __syncthreads();

  // ---- phase C: h0 = relu(x @ W0 + b0), stacked 2x4 partition ----
  {
    f32x4 acc[4][4];
    #pragma unroll
    for (int i = 0; i < 4; i++)
      #pragma unroll
      for (int cc = 0; cc < 4; cc++) acc[i][cc] = (f32x4){0.f,0.f,0.f,0.f};
    #pragma unroll
    for (int k0 = 0; k0 < NDIM; k0 += 32) {
      short8 bfw[4];
      #pragma unroll
      for (int cc = 0; cc < 4; cc++)
        bfw[cc] = *(const short8*)&Wt[cols4[cc] * NDIM + k0 + lk];
      short8 af[4];
      #pragma unroll
      for (int i = 0; i < 4; i++)
        af[i] = *(const short8*)&xls[srows[i] * XSTR + k0 + lk];
      #pragma unroll
      for (int i = 0; i < 4; i++)
        #pragma unroll
        for (int cc = 0; cc < 4; cc++)
          acc[i][cc] = __builtin_amdgcn_mfma_f32_16x16x32_bf16(af[i], bfw[cc], acc[i][cc], 0, 0, 0);
    }
    #pragma unroll
    for (int i = 0; i < 4; i++) {
      int row0 = rg * 64 + i * 16 + hi4;
      if (row0 >= 120) continue;
      int m = row0 / 40, p0 = row0 - m * 40;
      #pragma unroll
      for (int cc = 0; cc < 4; cc++) {
        int col = cols4[cc];
        float bias = b0[col];
        bfpk4 pk;
        #pragma unroll
        for (int rr = 0; rr < 4; rr++)
          pk.h[rr] = __float2bfloat16(fmaxf(acc[i][cc][rr] + bias, 0.f));
        *(uint2*)&hls[m][col][p0] = pk.u;
        *(uint2*)&gh0d[(m * NDIM + col) * 48 + p0] = pk.u;
      }
    }
  }
  __syncthreads();

  // ---- 4 GCN layers ----
  const float thetas[NLAYERS] = {0.40546510810816438f, 0.22314355131420976f,
                                 0.15415067982725836f, 0.11778303565638346f};
  #pragma unroll
  for (int li = 0; li < NLAYERS; li++) {
    float th = thetas[li], onemt = 1.f - th;
    const __hip_bfloat16* Wl = Wt + (li + 1) * NDIM * NDIM;

    // stage 1 (round-9 per-m form): sup = S_ext@[h;h_pm0;h_pm1] + 0.1*h0 -> xls
    {
      f32x4 acc[9][2];
      #pragma unroll
      for (int s = 0; s < 9; s++)
        #pragma unroll
        for (int c = 0; c < 2; c++) acc[s][c] = (f32x4){0.f,0.f,0.f,0.f};
      #pragma unroll
      for (int j = 0; j < 4; j++) {
        int kk = j * 32 + lk;
        short8 bfv[3][2];
        #pragma unroll
        for (int mm = 0; mm < 3; mm++) {
          int pm0 = (mm == 0) ? 1 : 0, pm1 = (mm == 2) ? 1 : 2;
          int srcm, brow;
          if (kk < 40)       { srcm = mm;  brow = kk; }
          else if (kk < 80)  { srcm = pm0; brow = kk - 40; }
          else if (kk < 120) { srcm = pm1; brow = kk - 80; }
          else               { srcm = pm1; brow = 32; }   // af zero there
          #pragma unroll
          for (int c = 0; c < 2; c++)
            bfv[mm][c] = *(const short8*)&hls[srcm][cols[c]][brow];
        }
        short8 af[9];
        #pragma unroll
        for (int s = 0; s < 9; s++)
          af[s] = *(const short8*)&sext[s / 3][arows[s % 3]][j * 32 + lk];
        #pragma unroll
        for (int s = 0; s < 9; s++)
          #pragma unroll
          for (int c = 0; c < 2; c++)
            acc[s][c] = __builtin_amdgcn_mfma_f32_16x16x32_bf16(af[s], bfv[s / 3][c], acc[s][c], 0, 0, 0);
      }
      #pragma unroll
      for (int s = 0; s < 9; s++) {
        int m = s / 3;
        int p0 = (s % 3) * 16 + hi4;
        if (p0 < L_DIA) {
          #pragma unroll
          for (int c = 0; c < 2; c++) {
            bfpk4 h0p;
            h0p.u = *(const uint2*)&gh0d[(m * NDIM + cols[c]) * 48 + p0];
            #pragma unroll
            for (int rr = 0; rr < 4; rr++)
              xls[(m * 40 + p0 + rr) * XSTR + cols[c]] =
                  __float2bfloat16(acc[s][c][rr] + 0.1f * bf2f(h0p.h[rr]));
          }
        }
      }
    }
    __syncthreads();

    // stage 2 (stacked 2x4): h_new = relu(theta*(sup@W) + (1-theta)*sup)
    {
      f32x4 o[4][4];
      #pragma unroll
      for (int i = 0; i < 4; i++)
        #pragma unroll
        for (int cc = 0; cc < 4; cc++) o[i][cc] = (f32x4){0.f,0.f,0.f,0.f};
      #pragma unroll
      for (int k0 = 0; k0 < NDIM; k0 += 32) {
        short8 bfw[4];
        #pragma unroll
        for (int cc = 0; cc < 4; cc++)
          bfw[cc] = *(const short8*)&Wl[cols4[cc] * NDIM + k0 + lk];
        short8 af[4];
        #pragma unroll
        for (int i = 0; i < 4; i++)
          af[i] = *(const short8*)&xls[srows[i] * XSTR + k0 + lk];
        #pragma unroll
        for (int i = 0; i < 4; i++)
          #pragma unroll
          for (int cc = 0; cc < 4; cc++)
            o[i][cc] = __builtin_amdgcn_mfma_f32_16x16x32_bf16(af[i], bfw[cc], o[i][cc], 0, 0, 0);
      }
      #pragma unroll
      for (int i = 0; i < 4; i++) {
        int row0 = rg * 64 + i * 16 + hi4;
        if (row0 >= 120) continue;
        int m = row0 / 40, p0 = row0 - m * 40;
        #pragma unroll
        for (int cc = 0; cc < 4; cc++) {
          int col = cols4[cc];
          if (li < NLAYERS - 1) {
            bfpk4 pk;
            #pragma unroll
            for (int rr = 0; rr < 4; rr++) {
              float supv = bf2f(xls[(row0 + rr) * XSTR + col]);
              pk.h[rr] = __float2bfloat16(fmaxf(th * o[i][cc][rr] + onemt * supv, 0.f));
            }
            *(uint2*)&hls[m][col][p0] = pk.u;
          } else {
            #pragma unroll
            for (int rr = 0; rr < 4; rr++) {
              float supv = bf2f(xls[(row0 + rr) * XSTR + col]);
              out[(b * L_DIA + p0 + rr) * 1536 + m * 512 + 256 + col] =
                  fmaxf(th * o[i][cc][rr] + onemt * supv, 0.f);
            }
          }
        }
      }
    }
    __syncthreads();
  }
}

// ---------------------------------------------------------------------------
extern "C" void kernel_launch(void* const* d_in, const int* in_sizes, int n_in,
                              void* d_out, int out_size, void* d_ws, size_t ws_size,
                              hipStream_t stream) {
  const float* a     = (const float*)d_in[0];
  const float* v     = (const float*)d_in[1];
  const float* lf    = (const float*)d_in[2];
  const float* qmask = (const float*)d_in[3];
  const float* spk   = (const float*)d_in[4];
  const float* W0    = (const float*)d_in[5];
  const float* b0    = (const float*)d_in[6];
  const float* Wc    = (const float*)d_in[7];
  float* out = (float*)d_out;

  __hip_bfloat16* Wt  = (__hip_bfloat16*)d_ws;          // 5*256*256 = 327,680 bf16
  __hip_bfloat16* gh0 = Wt + 5 * NDIM * NDIM;           // 100*3*256*48 bf16 = 7.4 MB

  k_wt<<<dim3(4, 4, 5), 256, 0, stream>>>(W0, Wc, Wt);
  k_main<<<B_DIA, 512, 0, stream>>>(a, v, lf, qmask, spk, b0, Wt, gh0, out);
}

// Round 17
// 63.127 us; speedup vs baseline: 1.3800x; 1.3326x over previous
//
#include <hip/hip_runtime.h>
#include <hip/hip_bf16.h>

#define N_UTT 4000
#define NDIM 256
#define B_DIA 100
#define L_DIA 40
#define NLAYERS 4

typedef __attribute__((ext_vector_type(8))) short short8;   // 8 bf16 (4 VGPRs)
typedef __attribute__((ext_vector_type(4))) float f32x4;    // MFMA acc

union bfpk4 { __hip_bfloat16 h[4]; uint2 u; };

static __device__ __forceinline__ float bf2f(__hip_bfloat16 h) {
  union { float f; unsigned u; } x;
  x.u = ((unsigned)*(unsigned short*)&h) << 16;
  return x.f;
}

// ---------------------------------------------------------------------------
// K_wt: weight transpose+bf16 via LDS tile: Wt[g][n][k] = W_g[k][n]
__global__ void k_wt(const float* __restrict__ W0, const float* __restrict__ Wc,
                     __hip_bfloat16* __restrict__ Wt) {
  int k0 = blockIdx.x * 64, n0 = blockIdx.y * 64, g = blockIdx.z;
  int t = threadIdx.x;
  const float* src = (g == 0) ? W0 : (Wc + (g - 1) * NDIM * NDIM);
  __shared__ float tile[64][65];
  #pragma unroll
  for (int it = 0; it < 16; it++) {
    int e = t + 256 * it;
    int row = e >> 6, col = e & 63;
    tile[row][col] = src[(k0 + row) * NDIM + n0 + col];
  }
  __syncthreads();
  #pragma unroll
  for (int it = 0; it < 16; it++) {
    int e = t + 256 * it;
    int row = e >> 6, col = e & 63;
    Wt[(g * NDIM + n0 + row) * NDIM + k0 + col] = __float2bfloat16(tile[col][row]);
  }
}

// ---------------------------------------------------------------------------
// K_main: one block per dialogue; whole network LDS-resident; k-outer
// register-blocked MFMA (af[9] x bf[2] -> 18 MFMA per k-step).
// This exact configuration (8 waves x 32 cols, acc[9][2], LDS blend re-read,
// zero mid-layer global traffic) is the verified 63.6 us optimum. Rounds
// 10-16 showed every deviation regresses via VGPR spill (>128), occupancy
// loss (1 wave/SIMD), or global latency on the serial critical path.
__global__ __launch_bounds__(512, 1) void k_main(
    const float* __restrict__ a, const float* __restrict__ v,
    const float* __restrict__ lf, const float* __restrict__ qmask,
    const float* __restrict__ spk, const float* __restrict__ b0,
    const __hip_bfloat16* __restrict__ Wt, float* __restrict__ out) {
  __shared__ __hip_bfloat16 xls[3][L_DIA][264];    // x, then sup   (63,360 B)
  __shared__ __hip_bfloat16 hls[3][NDIM][L_DIA];   // h transposed  (61,440 B)
  __shared__ __hip_bfloat16 sext[3][L_DIA][136];   // A_ext K=128   (32,640 B)
  __shared__ float invn[120];
  __shared__ float dinv[120];
  __shared__ float psum[120][4];

  int b = blockIdx.x;
  int t = threadIdx.x;
  int w = t >> 6, ln = t & 63;
  int l15 = ln & 15, lk = (ln >> 4) * 8;
  const float inv_pi = 0.31830988618379067f;

  int arows[3], cols[2];
  #pragma unroll
  for (int rt = 0; rt < 3; rt++) {
    int rr_ = rt * 16 + l15;
    arows[rt] = (rr_ < L_DIA) ? rr_ : (L_DIA - 1);
  }
  #pragma unroll
  for (int c = 0; c < 2; c++) cols[c] = w * 32 + c * 16 + l15;

  // ---- phase A: zero sext; build x; write out-x; x -> xls bf16 ----
  {
    unsigned int* sz = (unsigned int*)&sext[0][0][0];
    #pragma unroll
    for (int e = t; e < 3 * L_DIA * 136 / 2; e += 512) sz[e] = 0u;
  }
  for (int e = t; e < 120 * 64; e += 512) {
    int r = e >> 6, c4 = e & 63;
    int m = r / L_DIA, p = r - m * L_DIA;
    int i = b * L_DIA + p;
    float4 val;
    if (m == 0)      val = ((const float4*)a)[i * 64 + c4];
    else if (m == 1) val = ((const float4*)v)[i * 64 + c4];
    else {
      val = ((const float4*)lf)[i * 64 + c4];
      float q0 = qmask[(p * B_DIA + b) * 2 + 0];
      float q1 = qmask[(p * B_DIA + b) * 2 + 1];
      int s = (q1 > q0) ? 1 : 0;
      float4 sv = ((const float4*)spk)[s * 64 + c4];
      val.x += sv.x; val.y += sv.y; val.z += sv.z; val.w += sv.w;
    }
    ((float4*)out)[i * 384 + m * 128 + c4] = val;
    bfpk4 pk;
    pk.h[0] = __float2bfloat16(val.x); pk.h[1] = __float2bfloat16(val.y);
    pk.h[2] = __float2bfloat16(val.z); pk.h[3] = __float2bfloat16(val.w);
    *(uint2*)&xls[m][p][c4 * 4] = pk.u;
  }
  __syncthreads();

  // ---- row inverse norms (vectorized) ----
  if (t < 480) {
    int r = t >> 2, q4 = t & 3;
    int m = r / L_DIA, p = r - m * L_DIA;
    float s = 0.f;
    #pragma unroll
    for (int jj = 0; jj < 8; jj++) {
      short8 vv = *(const short8*)&xls[m][p][q4 * 64 + jj * 8];
      #pragma unroll
      for (int e = 0; e < 8; e++) {
        union { float f; unsigned u; } x;
        x.u = ((unsigned)(unsigned short)vv[e]) << 16;
        s += x.f * x.f;
      }
    }
    psum[r][q4] = s;
  }
  __syncthreads();
  if (t < 120) invn[t] = rsqrtf(psum[t][0] + psum[t][1] + psum[t][2] + psum[t][3]);
  __syncthreads();

  // ---- phase B: waves 0-2 self-sim 3x3; waves 3-5 pair diagonals ----
  if (w < 3) {
    int mA = w;
    f32x4 sacc[3][3];
    #pragma unroll
    for (int rt = 0; rt < 3; rt++)
      #pragma unroll
      for (int ct = 0; ct < 3; ct++) sacc[rt][ct] = (f32x4){0.f,0.f,0.f,0.f};
    #pragma unroll
    for (int k0 = 0; k0 < NDIM; k0 += 32) {
      short8 fr[3];
      #pragma unroll
      for (int rt = 0; rt < 3; rt++)
        fr[rt] = *(const short8*)&xls[mA][arows[rt]][k0 + lk];
      #pragma unroll
      for (int rt = 0; rt < 3; rt++)
        #pragma unroll
        for (int ct = 0; ct < 3; ct++)
          sacc[rt][ct] = __builtin_amdgcn_mfma_f32_16x16x32_bf16(fr[rt], fr[ct], sacc[rt][ct], 0, 0, 0);
    }
    #pragma unroll
    for (int rt = 0; rt < 3; rt++)
      #pragma unroll
      for (int ct = 0; ct < 3; ct++)
        #pragma unroll
        for (int rr = 0; rr < 4; rr++) {
          int row = rt * 16 + (ln >> 4) * 4 + rr;
          int col = ct * 16 + l15;
          if (row < L_DIA && col < L_DIA) {
            float cs = sacc[rt][ct][rr] * invn[mA * 40 + row] * invn[mA * 40 + col] * 0.99999f;
            cs = fminf(fmaxf(cs, -1.f), 1.f);
            sext[mA][row][col] = __float2bfloat16(1.f - acosf(cs) * inv_pi);
          }
        }
  } else if (w < 6) {
    int pi = w - 3;
    int mA = (pi == 2) ? 1 : 0, mB = (pi == 0) ? 1 : 2;
    int slotA = (pi == 0) ? 40 : 80, slotB = (pi == 2) ? 80 : 40;
    f32x4 dacc[3];
    #pragma unroll
    for (int rt = 0; rt < 3; rt++) dacc[rt] = (f32x4){0.f,0.f,0.f,0.f};
    #pragma unroll
    for (int k0 = 0; k0 < NDIM; k0 += 32) {
      short8 frA[3], frB[3];
      #pragma unroll
      for (int rt = 0; rt < 3; rt++) {
        frA[rt] = *(const short8*)&xls[mA][arows[rt]][k0 + lk];
        frB[rt] = *(const short8*)&xls[mB][arows[rt]][k0 + lk];
      }
      #pragma unroll
      for (int rt = 0; rt < 3; rt++)
        dacc[rt] = __builtin_amdgcn_mfma_f32_16x16x32_bf16(frA[rt], frB[rt], dacc[rt], 0, 0, 0);
    }
    #pragma unroll
    for (int rt = 0; rt < 3; rt++)
      #pragma unroll
      for (int rr = 0; rr < 4; rr++) {
        int row = rt * 16 + (ln >> 4) * 4 + rr;
        if (l15 == ((ln >> 4) * 4 + rr) && row < L_DIA) {
          float cs = dacc[rt][rr] * invn[mA * 40 + row] * invn[mB * 40 + row] * 0.99999f;
          cs = fminf(fmaxf(cs, -1.f), 1.f);
          __hip_bfloat16 vv = __float2bfloat16(1.f - acosf(cs) * inv_pi);
          sext[mA][row][slotA + row] = vv;
          sext[mB][row][slotB + row] = vv;
        }
      }
  }
  __syncthreads();

  // ---- degrees -> dinv ----
  if (t < 120) {
    int m = t / 40, p = t - m * 40;
    float d = 0.f;
    #pragma unroll 10
    for (int q = 0; q < 40; q++) d += bf2f(sext[m][p][q]);
    d += bf2f(sext[m][p][40 + p]) + bf2f(sext[m][p][80 + p]);
    dinv[t] = rsqrtf(d);
  }
  __syncthreads();
  // ---- normalize sext in place (fold 0.9) ----
  for (int e = t; e < 5040; e += 512) {
    if (e < 4800) {
      int m = e / 1600, rem = e - m * 1600;
      int p = rem / 40, q = rem - p * 40;
      sext[m][p][q] = __float2bfloat16(
          bf2f(sext[m][p][q]) * 0.9f * dinv[m * 40 + p] * dinv[m * 40 + q]);
    } else {
      int idx = e - 4800;
      int m = idx / 80, j = idx - m * 80;
      int which = j / 40, p = j - which * 40;
      int pmx = which ? ((m == 2) ? 1 : 2) : ((m == 0) ? 1 : 0);
      int k = 40 * (1 + which) + p;
      sext[m][p][k] = __float2bfloat16(
          bf2f(sext[m][p][k]) * 0.9f * dinv[m * 40 + p] * dinv[pmx * 40 + p]);
    }
  }
  __syncthreads();

  // ---- phase C: h0 = relu(x @ W0 + b0), k-outer blocked ----
  uint2 h0r[9][2];
  {
    f32x4 acc[9][2];
    #pragma unroll
    for (int s = 0; s < 9; s++)
      #pragma unroll
      for (int c = 0; c < 2; c++) acc[s][c] = (f32x4){0.f,0.f,0.f,0.f};
    #pragma unroll
    for (int k0 = 0; k0 < NDIM; k0 += 32) {
      short8 bfw[2];
      #pragma unroll
      for (int c = 0; c < 2; c++)
        bfw[c] = *(const short8*)&Wt[cols[c] * NDIM + k0 + lk];
      short8 af[9];
      #pragma unroll
      for (int s = 0; s < 9; s++)
        af[s] = *(const short8*)&xls[s / 3][arows[s % 3]][k0 + lk];
      #pragma unroll
      for (int s = 0; s < 9; s++)
        #pragma unroll
        for (int c = 0; c < 2; c++)
          acc[s][c] = __builtin_amdgcn_mfma_f32_16x16x32_bf16(af[s], bfw[c], acc[s][c], 0, 0, 0);
    }
    #pragma unroll
    for (int s = 0; s < 9; s++) {
      int p0 = (s % 3) * 16 + (ln >> 4) * 4;
      #pragma unroll
      for (int c = 0; c < 2; c++) {
        float bias = b0[cols[c]];
        bfpk4 pk;
        #pragma unroll
        for (int rr = 0; rr < 4; rr++)
          pk.h[rr] = __float2bfloat16(fmaxf(acc[s][c][rr] + bias, 0.f));
        h0r[s][c] = pk.u;
        if (p0 < L_DIA) *(uint2*)&hls[s / 3][cols[c]][p0] = pk.u;
      }
    }
  }
  __syncthreads();

  // ---- 4 GCN layers ----
  const float thetas[NLAYERS] = {0.40546510810816438f, 0.22314355131420976f,
                                 0.15415067982725836f, 0.11778303565638346f};
  #pragma unroll
  for (int li = 0; li < NLAYERS; li++) {
    float th = thetas[li], onemt = 1.f - th;
    const __hip_bfloat16* Wl = Wt + (li + 1) * NDIM * NDIM;

    // stage 1: sup = S_ext @ [h;h_pm0;h_pm1] + 0.1*h0 -> xls (bf16)
    {
      f32x4 acc[9][2];
      #pragma unroll
      for (int s = 0; s < 9; s++)
        #pragma unroll
        for (int c = 0; c < 2; c++) acc[s][c] = (f32x4){0.f,0.f,0.f,0.f};
      #pragma unroll
      for (int j = 0; j < 4; j++) {
        int kk = j * 32 + lk;
        short8 bfv[3][2];
        #pragma unroll
        for (int mm = 0; mm < 3; mm++) {
          int pm0 = (mm == 0) ? 1 : 0, pm1 = (mm == 2) ? 1 : 2;
          int srcm, brow;
          if (kk < 40)       { srcm = mm;  brow = kk; }
          else if (kk < 80)  { srcm = pm0; brow = kk - 40; }
          else if (kk < 120) { srcm = pm1; brow = kk - 80; }
          else               { srcm = pm1; brow = 32; }   // af zero there
          #pragma unroll
          for (int c = 0; c < 2; c++)
            bfv[mm][c] = *(const short8*)&hls[srcm][cols[c]][brow];
        }
        short8 af[9];
        #pragma unroll
        for (int s = 0; s < 9; s++)
          af[s] = *(const short8*)&sext[s / 3][arows[s % 3]][j * 32 + lk];
        #pragma unroll
        for (int s = 0; s < 9; s++)
          #pragma unroll
          for (int c = 0; c < 2; c++)
            acc[s][c] = __builtin_amdgcn_mfma_f32_16x16x32_bf16(af[s], bfv[s / 3][c], acc[s][c], 0, 0, 0);
      }
      #pragma unroll
      for (int s = 0; s < 9; s++) {
        int m = s / 3;
        int p0 = (s % 3) * 16 + (ln >> 4) * 4;
        #pragma unroll
        for (int c = 0; c < 2; c++) {
          bfpk4 h0p; h0p.u = h0r[s][c];
          if (p0 < L_DIA) {
            #pragma unroll
            for (int rr = 0; rr < 4; rr++)
              xls[m][p0 + rr][cols[c]] =
                  __float2bfloat16(acc[s][c][rr] + 0.1f * bf2f(h0p.h[rr]));
          }
        }
      }
    }
    __syncthreads();

    // stage 2: h_new = relu(theta*(sup@W) + (1-theta)*sup)
    {
      f32x4 o[9][2];
      #pragma unroll
      for (int s = 0; s < 9; s++)
        #pragma unroll
        for (int c = 0; c < 2; c++) o[s][c] = (f32x4){0.f,0.f,0.f,0.f};
      #pragma unroll
      for (int k0 = 0; k0 < NDIM; k0 += 32) {
        short8 bfw[2];
        #pragma unroll
        for (int c = 0; c < 2; c++)
          bfw[c] = *(const short8*)&Wl[cols[c] * NDIM + k0 + lk];
        short8 af[9];
        #pragma unroll
        for (int s = 0; s < 9; s++)
          af[s] = *(const short8*)&xls[s / 3][arows[s % 3]][k0 + lk];
        #pragma unroll
        for (int s = 0; s < 9; s++)
          #pragma unroll
          for (int c = 0; c < 2; c++)
            o[s][c] = __builtin_amdgcn_mfma_f32_16x16x32_bf16(af[s], bfw[c], o[s][c], 0, 0, 0);
      }
      #pragma unroll
      for (int s = 0; s < 9; s++) {
        int m = s / 3;
        int p0 = (s % 3) * 16 + (ln >> 4) * 4;
        if (p0 >= L_DIA) continue;
        #pragma unroll
        for (int c = 0; c < 2; c++) {
          int col = cols[c];
          if (li < NLAYERS - 1) {
            bfpk4 pk;
            #pragma unroll
            for (int rr = 0; rr < 4; rr++) {
              float supv = bf2f(xls[m][p0 + rr][col]);
              pk.h[rr] = __float2bfloat16(fmaxf(th * o[s][c][rr] + onemt * supv, 0.f));
            }
            *(uint2*)&hls[m][col][p0] = pk.u;
          } else {
            #pragma unroll
            for (int rr = 0; rr < 4; rr++) {
              float supv = bf2f(xls[m][p0 + rr][col]);
              out[(b * L_DIA + p0 + rr) * 1536 + m * 512 + 256 + col] =
                  fmaxf(th * o[s][c][rr] + onemt * supv, 0.f);
            }
          }
        }
      }
    }
    __syncthreads();
  }
}

// ---------------------------------------------------------------------------
extern "C" void kernel_launch(void* const* d_in, const int* in_sizes, int n_in,
                              void* d_out, int out_size, void* d_ws, size_t ws_size,
                              hipStream_t stream) {
  const float* a     = (const float*)d_in[0];
  const float* v     = (const float*)d_in[1];
  const float* lf    = (const float*)d_in[2];
  const float* qmask = (const float*)d_in[3];
  const float* spk   = (const float*)d_in[4];
  const float* W0    = (const float*)d_in[5];
  const float* b0    = (const float*)d_in[6];
  const float* Wc    = (const float*)d_in[7];
  float* out = (float*)d_out;

  __hip_bfloat16* Wt = (__hip_bfloat16*)d_ws;   // 5*256*256 bf16 = 640 KB

  k_wt<<<dim3(4, 4, 5), 256, 0, stream>>>(W0, Wc, Wt);
  k_main<<<B_DIA, 512, 0, stream>>>(a, v, lf, qmask, spk, b0, Wt, out);
}